// Round 14
// baseline (115.065 us; speedup 1.0000x reference)
//
#include <hip/hip_runtime.h>
#include <math.h>

// GptOssTopKRouter on MI355X — round 14: r13's wave-private no-barrier burst
// staging, spill-proofed.
//
// r13 post-mortem: WRITE_SIZE 157MB + VGPR 52 => compiler spilled the g[8]
// staging registers; the design never got a fair test. Fixes (only these):
//   1) staging regs halved: two float4[4] half-chunk buffers (gA = cols 0-31,
//      gB = cols 32-63), alternately written to LDS then reloaded.
//   2) per-lane min() clamp -> scalar per-(chunk,half) clamp (pad is
//      chunk-aligned; W pre-zeroed there).
//   3) __launch_bounds__(512,3): relax allocator cap (LDS, not VGPR, binds
//      occupancy at 2 blocks/CU = 4 waves/SIMD).
//
// Everything else identical to r13 (geometry certified conflict-free by its
// SQ_LDS_BANK_CONFLICT=0): logits^T = W[32,2880] @ X^T, 6 bf16 MFMA passes of
// 3-term trunc split (hh,mh,lh,hm,mm,hl; logit err ~2e-7, tie-safe top-4);
// 32x32x16 MFMA, W pre-split fragment-packed (590 KB d_ws, L2-resident,
// K padded 180->192 zeros). Block = 8 waves = 8 K-eighths x 32 tokens;
// grid 512. Wave-private single-buffered LDS tile [32][68] floats; within-
// wave DS ordering replaces barriers; loads issue in 128B-per-row bursts.

#define HIDDEN 2880
#define NE 32
#define TOPK 4
#define TPB 32            // tokens per block
#define NK16 192          // padded k16 steps (180 real + 12 zero)
#define RK16 180
#define VS (NK16 * 512)   // ver stride in wb: 98304 shorts
#define ROWF 68           // LDS row stride in floats
#define NCHW 6            // 64-float chunks per wave (6*64 = 384 padded K-eighth)

typedef __attribute__((ext_vector_type(8)))  short bf16x8;
typedef __attribute__((ext_vector_type(16))) float f32x16;

#define MFMA32(a, b, c) __builtin_amdgcn_mfma_f32_32x32x16_bf16((a), (b), (c), 0, 0, 0)

// Pre-kernel: W[32][2880] fp32 -> WB[3 ver][192 ks][512] bf16, exact 32x32
// A-fragment order: elem (l,j) = split_ver(W[l&31][ks*16 + (l>>5)*8 + j]);
// ks >= 180 slots are zero.
__global__ void wb_kernel(const float* __restrict__ w, unsigned short* __restrict__ wb) {
    int i = blockIdx.x * 256 + threadIdx.x;
    if (i >= 3 * VS) return;
    int j = i & 7;
    int l = (i >> 3) & 63;
    int rest = i >> 9;
    int ks  = rest % NK16;
    int ver = rest / NK16;
    unsigned short outv = 0;
    if (ks < RK16) {
        int e = l & 31;
        int k = ks * 16 + (l >> 5) * 8 + j;
        float v = w[e * HIDDEN + k];
        unsigned u = __float_as_uint(v);
        unsigned h = u >> 16;
        float r = v - __uint_as_float(u & 0xffff0000u);          // exact
        unsigned ur = __float_as_uint(r);
        unsigned m = ur >> 16;
        float r2 = r - __uint_as_float(ur & 0xffff0000u);        // exact
        unsigned lo = __float_as_uint(r2) >> 16;
        outv = (unsigned short)(ver == 0 ? h : (ver == 1 ? m : lo));
    }
    wb[i] = outv;
}

// split 8 consecutive fp32 -> 3 bf16x8 (hi, mid, lo), fully in-register
__device__ __forceinline__ void split24(float4 a, float4 b,
                                        bf16x8& H, bf16x8& M, bf16x8& L) {
    union { bf16x8 v; unsigned u[4]; } h, m, l;
    float f[8] = {a.x, a.y, a.z, a.w, b.x, b.y, b.z, b.w};
    unsigned hh[8], mm[8], ll[8];
#pragma unroll
    for (int i = 0; i < 8; ++i) {
        unsigned u = __float_as_uint(f[i]);
        hh[i] = u >> 16;
        float r = f[i] - __uint_as_float(u & 0xffff0000u);       // exact
        unsigned ur = __float_as_uint(r);
        mm[i] = ur >> 16;
        float r2 = r - __uint_as_float(ur & 0xffff0000u);        // exact
        ll[i] = __float_as_uint(r2) >> 16;
    }
#pragma unroll
    for (int i = 0; i < 4; ++i) {
        h.u[i] = hh[2 * i] | (hh[2 * i + 1] << 16);
        m.u[i] = mm[2 * i] | (mm[2 * i + 1] << 16);
        l.u[i] = ll[2 * i] | (ll[2 * i + 1] << 16);
    }
    H = h.v; M = m.v; L = l.v;
}

__global__ __launch_bounds__(512, 3)
void router_kernel(const float* __restrict__ x,
                   const unsigned short* __restrict__ wb,
                   const float* __restrict__ bias,
                   float* __restrict__ out_scores,
                   float* __restrict__ out_idx)
{
    __shared__ float pool[8 * TPB * ROWF];    // 69.6 KB; per-wave tiles; epilogue overlays

    const int tid  = threadIdx.x;
    const int lane = tid & 63;
    const int w    = tid >> 6;        // K-eighth 0..7
    const int col  = lane & 31;       // token (= B-frag col)
    const int kg   = lane >> 5;       // frag k group
    const int tok0 = blockIdx.x * TPB;

    float* tile = pool + w * (TPB * ROWF);    // this wave's private tile [32][ROWF]

    // staging: instr i covers rows 8i..8i+7, each row a contiguous 128B burst
    const int srow  = lane >> 3;              // 0..7 row-sub within instr
    const int sslot = lane & 7;               // float4 slot within half-chunk
    const float* xsrc = x + (size_t)(tok0 + srow) * HIDDEN + sslot * 4;
    float* sdst = tile + srow * ROWF + sslot * 4;

    const unsigned short* wk = wb + lane * 8;
    const int kbase = 384 * w;

    f32x16 acc = {0.f};

// load half h of chunk c into g[4]; scalar clamp keeps pad reads in-bounds
#define GLOADH(g, c, h) do {                                                      \
    const int ke_ = min(kbase + 64 * (c) + 32 * (h), HIDDEN - 32);                \
    _Pragma("unroll")                                                             \
    for (int i_ = 0; i_ < 4; ++i_)                                                \
        g[i_] = *(const float4*)(xsrc + (size_t)(8 * i_) * HIDDEN + ke_);         \
} while (0)

// write half h (cols 32h..32h+31) of the wave tile
#define SWRITEH(g, h) do { _Pragma("unroll")                                      \
    for (int i_ = 0; i_ < 4; ++i_)                                                \
        *(float4*)(sdst + 8 * i_ * ROWF + 32 * (h)) = g[i_];                      \
} while (0)

#define MFMA6(WH, WM, WL, XH, XM, XL) do {                                        \
    acc = MFMA32(WH, XH, acc);                                                    \
    acc = MFMA32(WM, XH, acc);                                                    \
    acc = MFMA32(WL, XH, acc);                                                    \
    acc = MFMA32(WH, XM, acc);                                                    \
    acc = MFMA32(WM, XM, acc);                                                    \
    acc = MFMA32(WH, XL, acc);                                                    \
} while (0)

// step s (0..3) of chunk c: 2 ds_read_b128 + 3 W dwordx4 + split + 6 MFMA
#define STEP(c, s) do {                                                           \
    const int ro_ = col * ROWF + (s) * 16 + kg * 8;                               \
    float4 a0_ = *(const float4*)(tile + ro_);                                    \
    float4 a1_ = *(const float4*)(tile + ro_ + 4);                                \
    const unsigned short* p_ = wk + (size_t)(24 * w + 4 * (c) + (s)) * 512;       \
    bf16x8 Wh_ = *(const bf16x8*)(p_);                                            \
    bf16x8 Wm_ = *(const bf16x8*)(p_ + VS);                                       \
    bf16x8 Wl_ = *(const bf16x8*)(p_ + 2 * VS);                                   \
    bf16x8 xh_, xm_, xl_;                                                         \
    split24(a0_, a1_, xh_, xm_, xl_);                                             \
    MFMA6(Wh_, Wm_, Wl_, xh_, xm_, xl_);                                          \
} while (0)

    float4 gA[4], gB[4];              // half-chunk staging (16 + 16 VGPR)

    GLOADH(gA, 0, 0);
    GLOADH(gB, 0, 1);

#pragma unroll 1
    for (int c = 0; c < NCHW; ++c) {
        SWRITEH(gA, 0);               // counted vmcnt for gA only (gB in flight)
        if (c < NCHW - 1) GLOADH(gA, c + 1, 0);
        STEP(c, 0); STEP(c, 1);       // consume cols 0..31 (in-order DS: safe)
        SWRITEH(gB, 1);
        if (c < NCHW - 1) GLOADH(gB, c + 1, 1);
        STEP(c, 2); STEP(c, 3);       // consume cols 32..63
    }

#undef GLOADH
#undef SWRITEH
#undef MFMA6
#undef STEP

    __syncthreads();                  // before overlaying pool with epilogue data

    // ---- C/D layout (m74/m101-verified 32x32): col=lane&31=token,
    //      row=(reg&3)+8*(reg>>2)+4*kg = expert ----
    float (*part)[TPB][36] = (float (*)[TPB][36])pool;        // 9216 floats
    float (*score)[33]     = (float (*)[33])(pool + 8 * TPB * 36);

#pragma unroll
    for (int r = 0; r < 16; ++r)
        part[w][col][(r & 3) + 8 * (r >> 2) + 4 * kg] = acc[r];
    __syncthreads();

    // ---- top-4 + softmax, one lane per token ----
    if (tid < TPB) {
        float lg[NE];
#pragma unroll
        for (int e = 0; e < NE; ++e) {
            float s = bias[e];
#pragma unroll
            for (int p = 0; p < 8; ++p) s += part[p][tid][e];
            lg[e] = s;
        }

        float vals[TOPK]; int idxs[TOPK]; unsigned chosen = 0u;
#pragma unroll
        for (int k = 0; k < TOPK; ++k) {
            float m = -INFINITY; int mi = 0;
#pragma unroll
            for (int e = 0; e < NE; ++e) {
                const bool take = (((chosen >> e) & 1u) == 0u) && (lg[e] > m);
                m  = take ? lg[e] : m;
                mi = take ? e : mi;
            }
            vals[k] = m; idxs[k] = mi; chosen |= (1u << (unsigned)mi);
        }
        const float mx = vals[0];
        float p[TOPK]; float sum = 0.f;
#pragma unroll
        for (int k = 0; k < TOPK; ++k) { p[k] = __expf(vals[k] - mx); sum += p[k]; }
        const float inv = 1.0f / sum;
#pragma unroll
        for (int e = 0; e < NE; ++e) {
            float v = 0.f;
#pragma unroll
            for (int k = 0; k < TOPK; ++k) v = (e == idxs[k]) ? p[k] * inv : v;
            score[tid][e] = v;
        }
        const int t = blockIdx.x * TPB + tid;
        float4 iv = make_float4((float)idxs[0], (float)idxs[1], (float)idxs[2], (float)idxs[3]);
        *reinterpret_cast<float4*>(out_idx + (size_t)t * TOPK) = iv;
    }
    __syncthreads();

    // ---- coalesced score store: 1024 floats, 512 threads x float2 ----
    {
        const int f = tid * 2;
        const int t = f >> 5, e = f & 31;
        float2 v = make_float2(score[t][e], score[t][e + 1]);
        *reinterpret_cast<float2*>(out_scores + (size_t)blockIdx.x * TPB * NE + f) = v;
    }
}

extern "C" void kernel_launch(void* const* d_in, const int* in_sizes, int n_in,
                              void* d_out, int out_size, void* d_ws, size_t ws_size,
                              hipStream_t stream)
{
    const float* x = (const float*)d_in[0];
    const float* w = (const float*)d_in[1];
    const float* b = (const float*)d_in[2];
    const int T = in_sizes[0] / HIDDEN;            // 16384 tokens

    unsigned short* wbuf = (unsigned short*)d_ws;  // 3*192*512 bf16 = 590 KB
    float* out        = (float*)d_out;
    float* out_scores = out;                       // [T, 32]
    float* out_idx    = out + (size_t)T * NE;      // [T, 4] as fp32 values

    wb_kernel<<<dim3((3 * VS + 255) / 256), dim3(256), 0, stream>>>(w, wbuf);
    router_kernel<<<dim3(T / TPB), dim3(512), 0, stream>>>(x, wbuf, b, out_scores, out_idx);
}

// Round 15
// 52.211 us; speedup vs baseline: 2.2038x; 2.2038x over previous
//
#include <hip/hip_runtime.h>
#include <math.h>

// GptOssTopKRouter on MI355X — round 15: r9 compute + wave-private burst
// staging, spill-proofed (named scalars, launch_bounds(512,2), f32x4 accs).
//
// r12-r14 all spilled (WRITE_SIZE 157-190MB vs 2.3MB of output) — the burst
// design never ran clean. Spill suspects removed: no register arrays, no
// tight VGPR cap, no f32x16 (16-contiguous-reg alloc fragmentation).
//
// Compute (r9-verified, 56us): logits^T = W[32,2880] @ X^T as 6 bf16 MFMA
// passes of 3-term trunc split (hh,mh,lh,hm,mm,hl; err ~2e-7, tie-safe).
// 16x16x32 MFMA; W pre-split fragment-packed WB[3][96ks][2et][512] (1.18MB
// d_ws, L2-resident; ks>=90 zero). X is the B operand: B-frag col=lane&15
// =token, k=(lane>>4)*8+j — read as 2 float4 from the wave's LDS tile and
// split to bf16 in registers.
// Staging (new): wave-private [16 rows][68] fp32 tile, single-buffered, NO
// barriers (within-wave DS ops are in-order; reads of chunk c issue before
// writes of chunk c+1 — correctness proven in r13). Chunk = 64 floats/row;
// 4 global dwordx4/chunk, each covering 8 rows x CONTIGUOUS 128B (4x bigger
// DRAM bursts than r9's 64B/row). Writes 2-way banked, reads 2-way: free.
// Block = 8 waves = 2 M-tiles x 4 K-quarters (768 padded floats = 12 chunks
// = 24 k32-steps; kq3 chunks 9-11 pad: X clamped, W zero). Grid 512.

#define HIDDEN 2880
#define NE 32
#define TOPK 4
#define TPB 32            // tokens per block
#define KSLOTS 96         // padded k32-steps (90 real + 6 zero)
#define VS (KSLOTS * 2 * 512)   // ver stride in wb: 98304 shorts
#define ROWF 68           // LDS tile row stride (floats)

typedef __attribute__((ext_vector_type(8))) short bf16x8;
typedef __attribute__((ext_vector_type(4))) float f32x4;

#define MFMA(a, b, c) __builtin_amdgcn_mfma_f32_16x16x32_bf16((a), (b), (c), 0, 0, 0)

// Pre-kernel (r9-verified): W[32][2880] fp32 -> WB[3 ver][96 ks][2 et][512]
// bf16, exact A-frag order: (l,j) = split_ver(W[et*16+(l&15)][ks*32+(l>>4)*8+j]);
// ks >= 90 slots zero.
__global__ void wb_kernel(const float* __restrict__ w, unsigned short* __restrict__ wb) {
    int i = blockIdx.x * 256 + threadIdx.x;
    if (i >= 3 * VS) return;
    int j = i & 7;
    int t = i >> 3;
    int l = t & 63;  t >>= 6;
    int et = t & 1;  t >>= 1;
    int ks = t % KSLOTS;
    int ver = t / KSLOTS;
    unsigned short outv = 0;
    if (ks < 90) {
        int e = et * 16 + (l & 15);
        int k = ks * 32 + (l >> 4) * 8 + j;
        float v = w[e * HIDDEN + k];
        unsigned u = __float_as_uint(v);
        unsigned h = u >> 16;
        float r = v - __uint_as_float(u & 0xffff0000u);          // exact
        unsigned ur = __float_as_uint(r);
        unsigned m = ur >> 16;
        float r2 = r - __uint_as_float(ur & 0xffff0000u);        // exact
        unsigned lo = __float_as_uint(r2) >> 16;
        outv = (unsigned short)(ver == 0 ? h : (ver == 1 ? m : lo));
    }
    wb[i] = outv;
}

// split 8 consecutive fp32 -> 3 bf16x8 (hi, mid, lo), fully in-register
__device__ __forceinline__ void split24(float4 a, float4 b,
                                        bf16x8& H, bf16x8& M, bf16x8& L) {
    union { bf16x8 v; unsigned u[4]; } h, m, l;
    float f[8] = {a.x, a.y, a.z, a.w, b.x, b.y, b.z, b.w};
    unsigned hh[8], mm[8], ll[8];
#pragma unroll
    for (int i = 0; i < 8; ++i) {
        unsigned u = __float_as_uint(f[i]);
        hh[i] = u >> 16;
        float r = f[i] - __uint_as_float(u & 0xffff0000u);       // exact
        unsigned ur = __float_as_uint(r);
        mm[i] = ur >> 16;
        float r2 = r - __uint_as_float(ur & 0xffff0000u);        // exact
        ll[i] = __float_as_uint(r2) >> 16;
    }
#pragma unroll
    for (int i = 0; i < 4; ++i) {
        h.u[i] = hh[2 * i] | (hh[2 * i + 1] << 16);
        m.u[i] = mm[2 * i] | (mm[2 * i + 1] << 16);
        l.u[i] = ll[2 * i] | (ll[2 * i + 1] << 16);
    }
    H = h.v; M = m.v; L = l.v;
}

__global__ __launch_bounds__(512, 2)
void router_kernel(const float* __restrict__ x,
                   const unsigned short* __restrict__ wb,
                   const float* __restrict__ bias,
                   float* __restrict__ out_scores,
                   float* __restrict__ out_idx)
{
    __shared__ float xt[8 * 16 * ROWF];    // 34.8 KB: per-wave tiles
    __shared__ float part[4][TPB][36];     // 18.4 KB: K-quarter partials
    __shared__ float score[TPB][33];       //  4.2 KB

    const int tid  = threadIdx.x;
    const int lane = tid & 63;
    const int w    = tid >> 6;
    const int wm   = w & 1;           // M-tile (16 tokens)
    const int kq   = w >> 1;          // K-quarter
    const int tl   = lane & 15;       // token (= B-frag col)

    float* tile = xt + w * (16 * ROWF);    // wave-private [16][ROWF]

    // staging: instr covers 8 rows x contiguous 128B; lane -> (srow, sslot)
    const int srow  = lane >> 3;           // 0..7
    const int sslot = lane & 7;            // 16B slot within 128B half-row
    const float* xs0 = x + (size_t)(blockIdx.x * TPB + wm * 16 + srow) * HIDDEN + sslot * 4;
    const float* xs1 = xs0 + (size_t)8 * HIDDEN;
    float* sd0 = tile + srow * ROWF + sslot * 4;
    float* sd1 = tile + (8 + srow) * ROWF + sslot * 4;

    const unsigned short* wk = wb + lane * 8;
    const int kbase = kq * 768;
    const int ks0   = kq * 24;
    // A-frag read base: row = tl, k-offset = (lane>>4)*8
    const int rbase = tl * ROWF + (lane >> 4) * 8;

    f32x4 acc0 = {0.f, 0.f, 0.f, 0.f};    // experts 0..15  x token tl
    f32x4 acc1 = {0.f, 0.f, 0.f, 0.f};    // experts 16..31 x token tl

    float4 g0, g1, g2, g3;                 // named staging (chunk: 2 rowgrps x 2 halves)
    bf16x8 Wa0, Wa1, Wa2, Wa3, Wa4, Wa5;   // W step buffer A (even steps)
    bf16x8 Wb0, Wb1, Wb2, Wb3, Wb4, Wb5;   // W step buffer B (odd steps)

#define GLOADC(c) do {                                                            \
    const int ko_ = min(kbase + 64 * (c), HIDDEN - 64);                           \
    g0 = *(const float4*)(xs0 + ko_);                                             \
    g1 = *(const float4*)(xs1 + ko_);                                             \
    g2 = *(const float4*)(xs0 + ko_ + 32);                                        \
    g3 = *(const float4*)(xs1 + ko_ + 32);                                        \
} while (0)

#define SWRITE() do {                                                             \
    *(float4*)(sd0)      = g0;                                                    \
    *(float4*)(sd1)      = g1;                                                    \
    *(float4*)(sd0 + 32) = g2;                                                    \
    *(float4*)(sd1 + 32) = g3;                                                    \
} while (0)

#define LOADW(W0, W1, W2, W3, W4, W5, sg) do {                                    \
    const unsigned short* p_ = wk + (size_t)min((sg), KSLOTS - 1) * 1024;         \
    W0 = *(const bf16x8*)(p_);                /* hi,  et0 */                      \
    W1 = *(const bf16x8*)(p_ + 512);          /* hi,  et1 */                      \
    W2 = *(const bf16x8*)(p_ + VS);           /* mid, et0 */                      \
    W3 = *(const bf16x8*)(p_ + VS + 512);     /* mid, et1 */                      \
    W4 = *(const bf16x8*)(p_ + 2 * VS);       /* lo,  et0 */                      \
    W5 = *(const bf16x8*)(p_ + 2 * VS + 512); /* lo,  et1 */                      \
} while (0)

// step st (0/1) of current chunk: 2 ds_read_b128 + split + 12 MFMA
#define STEP(st, W0, W1, W2, W3, W4, W5) do {                                     \
    float4 a0_ = *(const float4*)(tile + rbase + (st) * 32);                      \
    float4 a1_ = *(const float4*)(tile + rbase + (st) * 32 + 4);                  \
    bf16x8 xh_, xm_, xl_;                                                         \
    split24(a0_, a1_, xh_, xm_, xl_);                                             \
    acc0 = MFMA(W0, xh_, acc0);                                                   \
    acc1 = MFMA(W1, xh_, acc1);                                                   \
    acc0 = MFMA(W2, xh_, acc0);                                                   \
    acc1 = MFMA(W3, xh_, acc1);                                                   \
    acc0 = MFMA(W4, xh_, acc0);                                                   \
    acc1 = MFMA(W5, xh_, acc1);                                                   \
    acc0 = MFMA(W0, xm_, acc0);                                                   \
    acc1 = MFMA(W1, xm_, acc1);                                                   \
    acc0 = MFMA(W2, xm_, acc0);                                                   \
    acc1 = MFMA(W3, xm_, acc1);                                                   \
    acc0 = MFMA(W0, xl_, acc0);                                                   \
    acc1 = MFMA(W1, xl_, acc1);                                                   \
} while (0)

    // prologue: chunk0 -> LDS; chunk1 in regs; W steps 0,1 in regs
    GLOADC(0);
    SWRITE();                              // compiler inserts counted vmcnt
    GLOADC(1);
    LOADW(Wa0, Wa1, Wa2, Wa3, Wa4, Wa5, ks0);
    LOADW(Wb0, Wb1, Wb2, Wb3, Wb4, Wb5, ks0 + 1);

#pragma unroll 1
    for (int c = 0; c < 12; ++c) {
        STEP(0, Wa0, Wa1, Wa2, Wa3, Wa4, Wa5);          // ds_reads chunk c issued here
        LOADW(Wa0, Wa1, Wa2, Wa3, Wa4, Wa5, ks0 + 2 * c + 2);
        STEP(1, Wb0, Wb1, Wb2, Wb3, Wb4, Wb5);
        LOADW(Wb0, Wb1, Wb2, Wb3, Wb4, Wb5, ks0 + 2 * c + 3);
        if (c < 11) {
            SWRITE();                      // chunk c+1 -> LDS (in-order after reads)
            GLOADC(c + 2);                 // clamped; W zero in pad region
        }
    }

#undef GLOADC
#undef SWRITE
#undef LOADW
#undef STEP

    // ---- C/D layout (r7/r8/r9-verified): col=lane&15=token,
    //      row=(lane>>4)*4+j=expert ----
    {
        const int eb = (lane >> 4) * 4;
        *(f32x4*)&part[kq][wm * 16 + tl][eb]      = acc0;
        *(f32x4*)&part[kq][wm * 16 + tl][16 + eb] = acc1;
    }
    __syncthreads();

    // ---- top-4 + softmax, one lane per token ----
    if (tid < TPB) {
        float lg[NE];
#pragma unroll
        for (int e = 0; e < NE; ++e)
            lg[e] = part[0][tid][e] + part[1][tid][e]
                  + part[2][tid][e] + part[3][tid][e] + bias[e];

        float vals[TOPK]; int idxs[TOPK]; unsigned chosen = 0u;
#pragma unroll
        for (int k = 0; k < TOPK; ++k) {
            float m = -INFINITY; int mi = 0;
#pragma unroll
            for (int e = 0; e < NE; ++e) {
                const bool take = (((chosen >> e) & 1u) == 0u) && (lg[e] > m);
                m  = take ? lg[e] : m;
                mi = take ? e : mi;
            }
            vals[k] = m; idxs[k] = mi; chosen |= (1u << (unsigned)mi);
        }
        const float mx = vals[0];
        float p[TOPK]; float sum = 0.f;
#pragma unroll
        for (int k = 0; k < TOPK; ++k) { p[k] = __expf(vals[k] - mx); sum += p[k]; }
        const float inv = 1.0f / sum;
#pragma unroll
        for (int e = 0; e < NE; ++e) {
            float v = 0.f;
#pragma unroll
            for (int k = 0; k < TOPK; ++k) v = (e == idxs[k]) ? p[k] * inv : v;
            score[tid][e] = v;
        }
        const int t = blockIdx.x * TPB + tid;
        float4 iv = make_float4((float)idxs[0], (float)idxs[1], (float)idxs[2], (float)idxs[3]);
        *reinterpret_cast<float4*>(out_idx + (size_t)t * TOPK) = iv;
    }
    __syncthreads();

    // ---- coalesced score store: 1024 floats, 512 threads x float2 ----
    {
        const int f = tid * 2;
        const int t = f >> 5, e = f & 31;
        float2 v = make_float2(score[t][e], score[t][e + 1]);
        *reinterpret_cast<float2*>(out_scores + (size_t)blockIdx.x * TPB * NE + f) = v;
    }
}

extern "C" void kernel_launch(void* const* d_in, const int* in_sizes, int n_in,
                              void* d_out, int out_size, void* d_ws, size_t ws_size,
                              hipStream_t stream)
{
    const float* x = (const float*)d_in[0];
    const float* w = (const float*)d_in[1];
    const float* b = (const float*)d_in[2];
    const int T = in_sizes[0] / HIDDEN;            // 16384 tokens

    unsigned short* wbuf = (unsigned short*)d_ws;  // 3*96*2*512 bf16 = 1.18 MB
    float* out        = (float*)d_out;
    float* out_scores = out;                       // [T, 32]
    float* out_idx    = out + (size_t)T * NE;      // [T, 4] as fp32 values

    wb_kernel<<<dim3((3 * VS + 255) / 256), dim3(256), 0, stream>>>(w, wbuf);
    router_kernel<<<dim3(T / TPB), dim3(512), 0, stream>>>(x, wbuf, b, out_scores, out_idx);
}

// Round 16
// 50.201 us; speedup vs baseline: 2.2921x; 1.0400x over previous
//
#include <hip/hip_runtime.h>
#include <math.h>

// GptOssTopKRouter on MI355X — round 16: 1KB-burst block-cooperative staging
// with counted-vmcnt pipeline (T3/T4), 16x16x32 split-bf16 MFMA compute.
//
// Five structures pinned at 52-56us / ~3.5 TB/s X delivery; the untested
// variable is DRAM burst size per row-stream. Here each global_load_dwordx4
// covers ONE token-row's contiguous 1KB (64 lanes x 16B) — same request
// shape as the 7.2 TB/s fill. Double-buffered [32][260] tile; SWRITE of
// chunk c+1 waits (compiler-counted) vmcnt(4) on loads issued one full
// chunk earlier while chunk c+2's loads remain in flight; raw s_barrier
// only (no __syncthreads vmcnt(0) drain in the loop).
//
// Compute (r7-r15-verified): logits^T = W[32,2880] @ X^T, 6 bf16 MFMA
// passes of 3-term trunc split (hh,mh,lh,hm,mm,hl; logit err ~2e-7,
// tie-safe top-4). 16x16x32 MFMA; W pre-split fragment-packed
// WB[3][96ks][2et][512] (590 KB d_ws, L2-resident). K tail (2880 = 11.25
// chunks) handled in wb_kernel: chunk 11 loads x[2624..2879]; WB ks 88-93
// zero, ks 94-95 remapped to k=2816..2879 -> no per-lane clamps anywhere.
// Block = 512 thr = 8 waves; wave w = k-step w of every chunk (2 M-tiles,
// 4 f32x4 accs). Grid 512 -> 2 blocks/CU = 4 waves/SIMD.

#define HIDDEN 2880
#define NE 32
#define TOPK 4
#define TPB 32            // tokens per block
#define CKF 256           // k-floats per chunk per row
#define NCH 12            // chunks (11 full + remapped tail)
#define ROWF 260          // LDS row stride (floats)
#define KS_TOT 96         // 12 chunks x 8 k32-steps
#define VS (KS_TOT * 2 * 512)   // ver stride in wb: 98304 shorts

typedef __attribute__((ext_vector_type(8))) short bf16x8;
typedef __attribute__((ext_vector_type(4))) float f32x4;

#define MFMA(a, b, c) __builtin_amdgcn_mfma_f32_16x16x32_bf16((a), (b), (c), 0, 0, 0)

// W[32][2880] fp32 -> WB[3 ver][96 ks][2 et][512] bf16, A-frag order:
// (l,j) = split_ver(W[et*16+(l&15)][k]) where
//   ks < 88 : k = ks*32 + (l>>4)*8 + j                  (real)
//   88..93  : zero                                       (chunk-11 dup guard)
//   94,95   : k = 2624 + (ks-88)*32 + (l>>4)*8 + j       (= 2816..2879, real)
__global__ void wb_kernel(const float* __restrict__ w, unsigned short* __restrict__ wb) {
    int i = blockIdx.x * 256 + threadIdx.x;
    if (i >= 3 * VS) return;
    int j = i & 7;
    int t = i >> 3;
    int l = t & 63;  t >>= 6;
    int et = t & 1;  t >>= 1;
    int ks = t % KS_TOT;
    int ver = t / KS_TOT;
    unsigned short outv = 0;
    int k = -1;
    if (ks < 88)       k = ks * 32 + (l >> 4) * 8 + j;
    else if (ks >= 94) k = 2624 + (ks - 88) * 32 + (l >> 4) * 8 + j;
    if (k >= 0) {
        int e = et * 16 + (l & 15);
        float v = w[e * HIDDEN + k];
        unsigned u = __float_as_uint(v);
        unsigned h = u >> 16;
        float r = v - __uint_as_float(u & 0xffff0000u);          // exact
        unsigned ur = __float_as_uint(r);
        unsigned m = ur >> 16;
        float r2 = r - __uint_as_float(ur & 0xffff0000u);        // exact
        unsigned lo = __float_as_uint(r2) >> 16;
        outv = (unsigned short)(ver == 0 ? h : (ver == 1 ? m : lo));
    }
    wb[i] = outv;
}

// split 8 consecutive fp32 -> 3 bf16x8 (hi, mid, lo), in-register
__device__ __forceinline__ void split24(float4 a, float4 b,
                                        bf16x8& H, bf16x8& M, bf16x8& L) {
    union { bf16x8 v; unsigned u[4]; } h, m, l;
    float f[8] = {a.x, a.y, a.z, a.w, b.x, b.y, b.z, b.w};
    unsigned hh[8], mm[8], ll[8];
#pragma unroll
    for (int i = 0; i < 8; ++i) {
        unsigned u = __float_as_uint(f[i]);
        hh[i] = u >> 16;
        float r = f[i] - __uint_as_float(u & 0xffff0000u);       // exact
        unsigned ur = __float_as_uint(r);
        mm[i] = ur >> 16;
        float r2 = r - __uint_as_float(ur & 0xffff0000u);        // exact
        ll[i] = __float_as_uint(r2) >> 16;
    }
#pragma unroll
    for (int i = 0; i < 4; ++i) {
        h.u[i] = hh[2 * i] | (hh[2 * i + 1] << 16);
        m.u[i] = mm[2 * i] | (mm[2 * i + 1] << 16);
        l.u[i] = ll[2 * i] | (ll[2 * i + 1] << 16);
    }
    H = h.v; M = m.v; L = l.v;
}

__global__ __launch_bounds__(512, 4)
void router_kernel(const float* __restrict__ x,
                   const unsigned short* __restrict__ wb,
                   const float* __restrict__ bias,
                   float* __restrict__ out_scores,
                   float* __restrict__ out_idx)
{
    __shared__ float buf[2][TPB][ROWF];   // 66.56 KB; epilogue overlays

    const int tid  = threadIdx.x;
    const int lane = tid & 63;
    const int w    = tid >> 6;        // k-step within chunk, staging row group
    const int tl   = lane & 15;       // token within M-tile (B-frag col)
    const int kg   = lane >> 4;       // frag k group
    const int tok0 = blockIdx.x * TPB;

    // staging: wave w owns rows 4w..4w+3; one instr = one row's contiguous 1KB
    const float* xsr = x + (size_t)(tok0 + 4 * w) * HIDDEN + lane * 4;
    const unsigned short* wk = wb + lane * 8;

    f32x4 acc0 = {0.f, 0.f, 0.f, 0.f};   // mt0, experts 0-15
    f32x4 acc1 = {0.f, 0.f, 0.f, 0.f};   // mt0, experts 16-31
    f32x4 acc2 = {0.f, 0.f, 0.f, 0.f};   // mt1, experts 0-15
    f32x4 acc3 = {0.f, 0.f, 0.f, 0.f};   // mt1, experts 16-31

    float4 ga0, ga1, ga2, ga3, gb0, gb1, gb2, gb3;   // named staging regs

#define GLOAD(g0_, g1_, g2_, g3_, c) do {                                         \
    const int ko_ = ((c) < 11 ? (c) * CKF : 2624);                                \
    g0_ = *(const float4*)(xsr + ko_);                                            \
    g1_ = *(const float4*)(xsr + (size_t)HIDDEN + ko_);                           \
    g2_ = *(const float4*)(xsr + (size_t)2 * HIDDEN + ko_);                       \
    g3_ = *(const float4*)(xsr + (size_t)3 * HIDDEN + ko_);                       \
} while (0)

#define SWRITE(b, g0_, g1_, g2_, g3_) do {                                        \
    float* d_ = &buf[b][4 * w][0] + lane * 4;                                     \
    *(float4*)(d_)            = g0_;                                              \
    *(float4*)(d_ + ROWF)     = g1_;                                              \
    *(float4*)(d_ + 2 * ROWF) = g2_;                                              \
    *(float4*)(d_ + 3 * ROWF) = g3_;                                              \
} while (0)

// raw barrier only — __syncthreads would drain vmcnt(0) and kill the pipeline
#define BAR() do {                                                                \
    asm volatile("s_waitcnt lgkmcnt(0)" ::: "memory");                            \
    __builtin_amdgcn_s_barrier();                                                 \
} while (0)

#define COMPUTE(b, c) do {                                                        \
    const unsigned short* p_ = wk + (size_t)(8 * (c) + w) * 1024;                 \
    bf16x8 W0 = *(const bf16x8*)(p_);                                             \
    bf16x8 W1 = *(const bf16x8*)(p_ + 512);                                       \
    bf16x8 W2 = *(const bf16x8*)(p_ + VS);                                        \
    bf16x8 W3 = *(const bf16x8*)(p_ + VS + 512);                                  \
    bf16x8 W4 = *(const bf16x8*)(p_ + 2 * VS);                                    \
    bf16x8 W5 = *(const bf16x8*)(p_ + 2 * VS + 512);                              \
    const int xo_ = w * 32 + kg * 8;                                              \
    float4 a0_ = *(const float4*)(&buf[b][tl][xo_]);                              \
    float4 a1_ = *(const float4*)(&buf[b][tl][xo_ + 4]);                          \
    bf16x8 xh_, xm_, xl_;                                                         \
    split24(a0_, a1_, xh_, xm_, xl_);                                             \
    acc0 = MFMA(W0, xh_, acc0);  acc1 = MFMA(W1, xh_, acc1);                      \
    acc0 = MFMA(W2, xh_, acc0);  acc1 = MFMA(W3, xh_, acc1);                      \
    acc0 = MFMA(W4, xh_, acc0);  acc1 = MFMA(W5, xh_, acc1);                      \
    acc0 = MFMA(W0, xm_, acc0);  acc1 = MFMA(W1, xm_, acc1);                      \
    acc0 = MFMA(W2, xm_, acc0);  acc1 = MFMA(W3, xm_, acc1);                      \
    acc0 = MFMA(W0, xl_, acc0);  acc1 = MFMA(W1, xl_, acc1);                      \
    float4 b0_ = *(const float4*)(&buf[b][16 + tl][xo_]);                         \
    float4 b1_ = *(const float4*)(&buf[b][16 + tl][xo_ + 4]);                     \
    split24(b0_, b1_, xh_, xm_, xl_);                                             \
    acc2 = MFMA(W0, xh_, acc2);  acc3 = MFMA(W1, xh_, acc3);                      \
    acc2 = MFMA(W2, xh_, acc2);  acc3 = MFMA(W3, xh_, acc3);                      \
    acc2 = MFMA(W4, xh_, acc2);  acc3 = MFMA(W5, xh_, acc3);                      \
    acc2 = MFMA(W0, xm_, acc2);  acc3 = MFMA(W1, xm_, acc3);                      \
    acc2 = MFMA(W2, xm_, acc2);  acc3 = MFMA(W3, xm_, acc3);                      \
    acc2 = MFMA(W0, xl_, acc2);  acc3 = MFMA(W1, xl_, acc3);                      \
} while (0)

    // prologue: buf0 <- chunk0; gb = chunk1; ga = chunk2 (stays in flight)
    GLOAD(ga0, ga1, ga2, ga3, 0);
    GLOAD(gb0, gb1, gb2, gb3, 1);
    SWRITE(0, ga0, ga1, ga2, ga3);        // counted vmcnt: waits ga only
    GLOAD(ga0, ga1, ga2, ga3, 2);
    BAR();

#pragma unroll 1
    for (int i = 0; i < 6; ++i) {
        const int c0 = 2 * i;
        SWRITE(1, gb0, gb1, gb2, gb3);    // chunk c0+1; vmcnt(4): ga in flight
        if (i < 5) GLOAD(gb0, gb1, gb2, gb3, c0 + 3);
        COMPUTE(0, c0);
        BAR();                            // buf1 ready; buf0 reads complete
        if (i < 5) SWRITE(0, ga0, ga1, ga2, ga3);   // chunk c0+2
        if (i < 4) GLOAD(ga0, ga1, ga2, ga3, c0 + 4);
        COMPUTE(1, c0 + 1);
        BAR();                            // buf0 ready; buf1 reads complete
    }

#undef GLOAD
#undef SWRITE
#undef BAR
#undef COMPUTE

    __syncthreads();                      // safe now (no loads outstanding)

    // ---- epilogue overlays buf: C/D layout (r7-r15-verified):
    //      col=lane&15=token, row=(lane>>4)*4+j=expert ----
    float* pool = &buf[0][0][0];
    // part[8][32][36] = 9216 floats; score[32][33] follows
#define PART(p, t, e) pool[((p) * TPB + (t)) * 36 + (e)]
    {
        const int eb = kg * 4;
        *(f32x4*)&PART(w, tl, eb)       = acc0;
        *(f32x4*)&PART(w, tl, 16 + eb)  = acc1;
        *(f32x4*)&PART(w, 16 + tl, eb)      = acc2;
        *(f32x4*)&PART(w, 16 + tl, 16 + eb) = acc3;
    }
    __syncthreads();

    float* score = pool + 8 * TPB * 36;   // [32][33]
    if (tid < TPB) {
        float lg[NE];
#pragma unroll
        for (int e = 0; e < NE; ++e) {
            float s = bias[e];
#pragma unroll
            for (int p = 0; p < 8; ++p) s += PART(p, tid, e);
            lg[e] = s;
        }

        float vals[TOPK]; int idxs[TOPK]; unsigned chosen = 0u;
#pragma unroll
        for (int k = 0; k < TOPK; ++k) {
            float m = -INFINITY; int mi = 0;
#pragma unroll
            for (int e = 0; e < NE; ++e) {
                const bool take = (((chosen >> e) & 1u) == 0u) && (lg[e] > m);
                m  = take ? lg[e] : m;
                mi = take ? e : mi;
            }
            vals[k] = m; idxs[k] = mi; chosen |= (1u << (unsigned)mi);
        }
        const float mx = vals[0];
        float p[TOPK]; float sum = 0.f;
#pragma unroll
        for (int k = 0; k < TOPK; ++k) { p[k] = __expf(vals[k] - mx); sum += p[k]; }
        const float inv = 1.0f / sum;
#pragma unroll
        for (int e = 0; e < NE; ++e) {
            float v = 0.f;
#pragma unroll
            for (int k = 0; k < TOPK; ++k) v = (e == idxs[k]) ? p[k] * inv : v;
            score[tid * 33 + e] = v;
        }
        const int t = tok0 + tid;
        float4 iv = make_float4((float)idxs[0], (float)idxs[1], (float)idxs[2], (float)idxs[3]);
        *reinterpret_cast<float4*>(out_idx + (size_t)t * TOPK) = iv;
    }
    __syncthreads();

    // coalesced score store: 1024 floats, 512 threads x float2
    {
        const int f = tid * 2;
        const int t = f >> 5, e = f & 31;
        float2 v = make_float2(score[t * 33 + e], score[t * 33 + e + 1]);
        *reinterpret_cast<float2*>(out_scores + (size_t)blockIdx.x * TPB * NE + f) = v;
    }
#undef PART
}

extern "C" void kernel_launch(void* const* d_in, const int* in_sizes, int n_in,
                              void* d_out, int out_size, void* d_ws, size_t ws_size,
                              hipStream_t stream)
{
    const float* x = (const float*)d_in[0];
    const float* w = (const float*)d_in[1];
    const float* b = (const float*)d_in[2];
    const int T = in_sizes[0] / HIDDEN;            // 16384 tokens

    unsigned short* wbuf = (unsigned short*)d_ws;  // 3*96*2*512 bf16 = 1.18 MB
    float* out        = (float*)d_out;
    float* out_scores = out;                       // [T, 32]
    float* out_idx    = out + (size_t)T * NE;      // [T, 4] as fp32 values

    wb_kernel<<<dim3((3 * VS + 255) / 256), dim3(256), 0, stream>>>(w, wbuf);
    router_kernel<<<dim3(T / TPB), dim3(512), 0, stream>>>(x, wbuf, b, out_scores, out_idx);
}